// Round 2
// baseline (280.679 us; speedup 1.0000x reference)
//
#include <hip/hip_runtime.h>
#include <cstdint>
#include <cstddef>

#define WS 64
#define SHIFT 32
#define WTOT 8192
#define NWIN 128
#define SCALE_F 0.125f

typedef __bf16 bf16x8 __attribute__((ext_vector_type(8)));
typedef __bf16 bf16x4 __attribute__((ext_vector_type(4)));
typedef float f32x4 __attribute__((ext_vector_type(4)));

// u16-unit swizzle for [64][64]-u16 tiles (K hi/lo, V^T hi/lo).
// byte ^= ((row>>1)&7)<<4 — proven conflict-free for all access patterns (r1).
__device__ __forceinline__ int swz16(int row, int col) {
  return (row * WS + col) ^ (((row >> 1) & 7) << 3);
}

// f32-unit swizzle for the [64][64]-f32 P/X overlay buffer.
// mask uses col bits {2,4} keyed on row bits 2-3:
//  - scalar b32 writes (lanes = 4 rows x 16 cols): <=2-way (free per m136)
//  - b128 A-fragment reads (rows=lrow, col=quad*8): 8 lanes/bank-group (min)
//  - b128 row readback (i-major, col=i*16+quad*4): 8 lanes/bank-group (min)
// bits 0-1 untouched => float4 granules stay contiguous/aligned.
__device__ __forceinline__ int swz32(int row, int col) {
  const int q2 = (row >> 2) & 3;
  return row * WS + (col ^ (((q2 & 1) << 4) | ((q2 >> 1) << 2)));
}

// One block (256 thr = 4 waves) per 64x64 window. 4096 blocks.
// LDS = 32768 B exactly -> 5 blocks/CU.
__global__ __launch_bounds__(256, 5) void win_attn(
    const float* __restrict__ q, const float* __restrict__ k,
    const float* __restrict__ v, const float* __restrict__ table,
    float* __restrict__ xout, float* __restrict__ attn_out) {
  __shared__ __align__(16) unsigned short s_mem[4 * WS * WS];  // 32 KiB
  unsigned short* const s_khi  = s_mem;                 // later: f32 P/X (with s_klo)
  unsigned short* const s_klo  = s_mem + WS * WS;
  unsigned short* const s_vthi = s_mem + 2 * WS * WS;   // V^T: [c][m]
  unsigned short* const s_vtlo = s_mem + 3 * WS * WS;
  float* const s_p = (float*)s_mem;                     // 16 KiB overlay

  const int t = threadIdx.x;
  const int b = blockIdx.x;            // window id 0..4095
  const int batch = b >> 7;
  const int win = b & (NWIN - 1);
  const int lane = t & 63;
  const int wave = t >> 6;             // 0..3 -> rows [16w,16w+16)
  const int lrow = lane & 15;
  const int quad = lane >> 4;

  // ---------- stage K -> hi/lo bf16 (native casts; b128 swizzled writes) ----------
  {
    const int lr = t >> 2;             // row 0..63
    const int lc = (t & 3) << 4;       // col base 0,16,32,48
    const int grow = (win * WS + lr + SHIFT) & (WTOT - 1);
    const float* kp = k + ((size_t)batch * WTOT + grow) * WS + lc;
#pragma unroll
    for (int s = 0; s < 2; ++s) {
      const float4 x0 = *(const float4*)(kp + 8 * s);
      const float4 x1 = *(const float4*)(kp + 8 * s + 4);
      const float a[8] = {x0.x, x0.y, x0.z, x0.w, x1.x, x1.y, x1.z, x1.w};
      bf16x8 hv, lv;
#pragma unroll
      for (int e = 0; e < 8; ++e) {
        const __bf16 h = (__bf16)a[e];
        hv[e] = h;
        lv[e] = (__bf16)(a[e] - (float)h);
      }
      const int idx = swz16(lr, lc + 8 * s);
      *(bf16x8*)(s_khi + idx) = hv;
      *(bf16x8*)(s_klo + idx) = lv;
    }
  }

  // ---------- stage V^T: 4x4 register micro-transpose, b64 swizzled writes ----------
  {
    const int m0 = (t >> 4) << 2;      // 4 source rows m0..m0+3
    const int c0 = (t & 15) << 2;      // 4 cols c0..c0+3
    float4 vr[4];
#pragma unroll
    for (int j = 0; j < 4; ++j) {
      const int grow = (win * WS + m0 + j + SHIFT) & (WTOT - 1);
      vr[j] = *(const float4*)(v + ((size_t)batch * WTOT + grow) * WS + c0);
    }
    const float vb[4][4] = {{vr[0].x, vr[0].y, vr[0].z, vr[0].w},
                            {vr[1].x, vr[1].y, vr[1].z, vr[1].w},
                            {vr[2].x, vr[2].y, vr[2].z, vr[2].w},
                            {vr[3].x, vr[3].y, vr[3].z, vr[3].w}};
#pragma unroll
    for (int e = 0; e < 4; ++e) {      // one V^T row segment per output col
      bf16x4 hv, lv;
#pragma unroll
      for (int j = 0; j < 4; ++j) {
        const float x = vb[j][e];
        const __bf16 h = (__bf16)x;
        hv[j] = h;
        lv[j] = (__bf16)(x - (float)h);
      }
      const int idx = swz16(c0 + e, m0);
      *(bf16x4*)(s_vthi + idx) = hv;
      *(bf16x4*)(s_vtlo + idx) = lv;
    }
  }

  // ---------- Q fragments straight global->reg (wave-private rows; no LDS) ----------
  bf16x8 qfhi[2], qflo[2];
  {
    const int grow = (win * WS + wave * 16 + lrow + SHIFT) & (WTOT - 1);
    const float* qp = q + ((size_t)batch * WTOT + grow) * WS + quad * 8;
#pragma unroll
    for (int kh = 0; kh < 2; ++kh) {
      const float4 x0 = *(const float4*)(qp + kh * 32);
      const float4 x1 = *(const float4*)(qp + kh * 32 + 4);
      const float a[8] = {x0.x, x0.y, x0.z, x0.w, x1.x, x1.y, x1.z, x1.w};
      bf16x8 hv, lv;
#pragma unroll
      for (int e = 0; e < 8; ++e) {
        const __bf16 h = (__bf16)a[e];
        hv[e] = h;
        lv[e] = (__bf16)(a[e] - (float)h);
      }
      qfhi[kh] = hv;
      qflo[kh] = lv;
    }
  }

  // ---------- bias + shift-mask folded into registers (L1-resident table) ----------
  float biasr[4][4];
  {
    const bool masked = (win == NWIN - 1);
    const float* tb = table + (WS - 1);
#pragma unroll
    for (int reg = 0; reg < 4; ++reg) {
      const int r = wave * 16 + quad * 4 + reg;
#pragma unroll
      for (int j = 0; j < 4; ++j) {
        const int m = j * 16 + lrow;
        float bv = __ldg(tb + (r - m));
        if (masked && (((r ^ m) & 32) != 0)) bv -= 100.0f;
        biasr[reg][j] = bv;
      }
    }
  }
  __syncthreads();  // K, V^T visible

  // ---------- S = Q K^T via split-bf16 MFMA ----------
  const f32x4 z4 = {0.f, 0.f, 0.f, 0.f};
  f32x4 acc[4] = {z4, z4, z4, z4};
#pragma unroll
  for (int kh = 0; kh < 2; ++kh) {
    const int k0 = kh * 32 + quad * 8;
    const bf16x8 ahi = qfhi[kh];
    const bf16x8 alo = qflo[kh];
#pragma unroll
    for (int j = 0; j < 4; ++j) {
      const int idx = swz16(j * 16 + lrow, k0);
      const bf16x8 bhi = *(const bf16x8*)(s_khi + idx);
      const bf16x8 blo = *(const bf16x8*)(s_klo + idx);
      acc[j] = __builtin_amdgcn_mfma_f32_16x16x32_bf16(ahi, bhi, acc[j], 0, 0, 0);
      acc[j] = __builtin_amdgcn_mfma_f32_16x16x32_bf16(alo, bhi, acc[j], 0, 0, 0);
      acc[j] = __builtin_amdgcn_mfma_f32_16x16x32_bf16(ahi, blo, acc[j], 0, 0, 0);
    }
  }

  // ---------- register softmax (rows split across the 16 lanes of a quad) ----------
  float p[4][4];  // [reg][j]
#pragma unroll
  for (int reg = 0; reg < 4; ++reg) {
    float val[4];
    float vmax = -1e30f;
#pragma unroll
    for (int j = 0; j < 4; ++j) {
      const float s = acc[j][reg] * SCALE_F + biasr[reg][j];
      val[j] = s;
      vmax = fmaxf(vmax, s);
    }
#pragma unroll
    for (int off = 1; off < 16; off <<= 1)
      vmax = fmaxf(vmax, __shfl_xor(vmax, off, 64));
    float sum = 0.f;
#pragma unroll
    for (int j = 0; j < 4; ++j) {
      val[j] = __expf(val[j] - vmax);
      sum += val[j];
    }
#pragma unroll
    for (int off = 1; off < 16; off <<= 1)
      sum += __shfl_xor(sum, off, 64);
    const float inv = 1.0f / sum;
#pragma unroll
    for (int j = 0; j < 4; ++j) p[reg][j] = val[j] * inv;
  }

  __syncthreads();  // all waves' K-fragment reads done -> khi/klo reusable as f32 P

  // ---------- restage P as f32 into overlay (wave-local 16-row slab) ----------
#pragma unroll
  for (int reg = 0; reg < 4; ++reg) {
    const int r = wave * 16 + quad * 4 + reg;
#pragma unroll
    for (int j = 0; j < 4; ++j) {
      s_p[swz32(r, j * 16 + lrow)] = p[reg][j];
    }
  }

  // ---------- attn: coalesced float4 readback + dwordx4 stores (no barrier:
  // wave-local slab; DS pipe is in-order per wave) ----------
  {
    const int r = wave * 16 + lrow;
    float* arow = attn_out + (size_t)b * (WS * WS) + (size_t)r * WS;
#pragma unroll
    for (int i = 0; i < 4; ++i) {
      const int c = i * 16 + quad * 4;   // i-major: 64B contiguous per row
      *(float4*)(arow + c) = *(const float4*)(s_p + swz32(r, c));
    }
  }

  // ---------- X = P V via split-bf16 MFMA (A-fragments split from exact f32 P) ----------
  f32x4 xacc[4] = {z4, z4, z4, z4};
#pragma unroll
  for (int kh = 0; kh < 2; ++kh) {
    const int c0 = kh * 32 + quad * 8;
    const int r = wave * 16 + lrow;
    const float4 a0 = *(const float4*)(s_p + swz32(r, c0));
    const float4 a1 = *(const float4*)(s_p + swz32(r, c0 + 4));
    const float pa[8] = {a0.x, a0.y, a0.z, a0.w, a1.x, a1.y, a1.z, a1.w};
    bf16x8 phi, plo;
#pragma unroll
    for (int e = 0; e < 8; ++e) {
      const __bf16 h = (__bf16)pa[e];
      phi[e] = h;
      plo[e] = (__bf16)(pa[e] - (float)h);
    }
#pragma unroll
    for (int j = 0; j < 4; ++j) {
      const int idx = swz16(j * 16 + lrow, c0);
      const bf16x8 vhi = *(const bf16x8*)(s_vthi + idx);
      const bf16x8 vlo = *(const bf16x8*)(s_vtlo + idx);
      xacc[j] = __builtin_amdgcn_mfma_f32_16x16x32_bf16(phi, vhi, xacc[j], 0, 0, 0);
      xacc[j] = __builtin_amdgcn_mfma_f32_16x16x32_bf16(plo, vhi, xacc[j], 0, 0, 0);
      xacc[j] = __builtin_amdgcn_mfma_f32_16x16x32_bf16(phi, vlo, xacc[j], 0, 0, 0);
    }
  }

  // ---------- X through LDS slab (own rows; reads above precede writes in
  // wave program order) then coalesced dwordx4 stores with reverse shift ----------
#pragma unroll
  for (int reg = 0; reg < 4; ++reg) {
    const int r = wave * 16 + quad * 4 + reg;
#pragma unroll
    for (int j = 0; j < 4; ++j) {
      s_p[swz32(r, j * 16 + lrow)] = xacc[j][reg];
    }
  }
  {
    const int r = wave * 16 + lrow;
    const int gr = (win * WS + r + SHIFT) & (WTOT - 1);
    float* xrow = xout + ((size_t)batch * WTOT + gr) * WS;
#pragma unroll
    for (int i = 0; i < 4; ++i) {
      const int c = i * 16 + quad * 4;
      *(float4*)(xrow + c) = *(const float4*)(s_p + swz32(r, c));
    }
  }
}

extern "C" void kernel_launch(void* const* d_in, const int* in_sizes, int n_in,
                              void* d_out, int out_size, void* d_ws, size_t ws_size,
                              hipStream_t stream) {
  (void)in_sizes; (void)n_in; (void)out_size; (void)d_ws; (void)ws_size;
  const float* q = (const float*)d_in[0];
  const float* k = (const float*)d_in[1];
  const float* v = (const float*)d_in[2];
  const float* table = (const float*)d_in[3];
  float* xout = (float*)d_out;                               // (32, 8192, 64)
  float* attn = (float*)d_out + (size_t)32 * WTOT * WS;      // (4096, 64, 64)
  win_attn<<<dim3(4096), dim3(256), 0, stream>>>(q, k, v, table, xout, attn);
}